// Round 8
// baseline (267.679 us; speedup 1.0000x reference)
//
#include <hip/hip_runtime.h>
#include <hip/hip_bf16.h>
#include <math.h>

// Problem dims: B=16,S=512,W=5,D=200,H=768  (BS=8192 rows, M1=40960 word-rows)
// Math: Ct = W2@attn_W^T; T = tanh(E@W1+b1); P = x@Ct^T; alpha = softmax(T_w.P+mask)
//       S = sum_w alpha_w T_w; H = x + S@W2 + b2; out = LN(H)*gamma+beta
// R17: tgemm post-mortem of R15/R16 (65us, occ 8.5% = 1 wave/SIMD): ALL prior
//      tgemm variants ran 4-wave blocks at ~1 block/CU -> one wave per SIMD,
//      zero latency hiding. Also R0's 1920-block version staged 245MB A+B
//      (A re-read 6x, B 320x) = 5.6TB/s = slow-tier ceiling. New tgemm:
//      320 blocks x 512 THREADS (8 waves = 2/SIMD even at 1 block/CU); each
//      block owns 128 rows x full N=768: A staged ONCE (64KB all-K; slow-tier
//      A traffic 126->21MB), B per nt from L2 (384KB, XCD-resident). Per nt:
//      stage B 64KB -> one vmcnt(0) -> 4 K-steps with NO barriers -> 2-pass
//      epilogue (rep 16.9KB). LDS 145KB. Everything else verbatim R14.

typedef __attribute__((ext_vector_type(8))) short bf16x8;
typedef __attribute__((ext_vector_type(4))) float f32x4;

__device__ __forceinline__ unsigned short f2bf_bits(float f) {
    __hip_bfloat16 h = __float2bfloat16(f);
    return *reinterpret_cast<unsigned short*>(&h);
}
__device__ __forceinline__ float bf_bits2f(unsigned short u) {
    union { unsigned int i; float f; } v; v.i = ((unsigned int)u) << 16; return v.f;
}
__device__ __forceinline__ float tanh_fast(float x) {
    float xc = fminf(fmaxf(x, -9.f), 9.f);
    float t  = __expf(2.f * xc);
    return (t - 1.f) * __builtin_amdgcn_rcpf(t + 1.f);
}
__device__ __forceinline__ bf16x8 pack8(float4 a, float4 b) {
    union { bf16x8 v; unsigned short s[8]; } u;
    u.s[0]=f2bf_bits(a.x); u.s[1]=f2bf_bits(a.y); u.s[2]=f2bf_bits(a.z); u.s[3]=f2bf_bits(a.w);
    u.s[4]=f2bf_bits(b.x); u.s[5]=f2bf_bits(b.y); u.s[6]=f2bf_bits(b.z); u.s[7]=f2bf_bits(b.w);
    return u.v;
}

__device__ __forceinline__ void async_cp16(const void* g, void* lds) {
#if __has_builtin(__builtin_amdgcn_global_load_lds)
    auto gp = (const __attribute__((address_space(1))) unsigned int*)g;
    auto lp = (__attribute__((address_space(3))) unsigned int*)lds;
    __builtin_amdgcn_global_load_lds(gp, lp, 16, 0, 0);
#else
    *(uint4*)lds = *(const uint4*)g;
#endif
}

__device__ __forceinline__ void sched_fence()  { asm volatile("" ::: "memory"); }
__device__ __forceinline__ void wait8_barrier(){ asm volatile("s_waitcnt vmcnt(8)\ns_barrier" ::: "memory"); }
__device__ __forceinline__ void wait0_barrier(){ asm volatile("s_waitcnt vmcnt(0)\ns_barrier" ::: "memory"); }
__device__ __forceinline__ void barrier_only() { asm volatile("s_barrier" ::: "memory"); }
__device__ __forceinline__ void lgkm_barrier() { asm volatile("s_waitcnt lgkmcnt(0)\ns_barrier" ::: "memory"); }

// ---------- MFMA bf16 GEMM body: D = A[M,K] @ Bt[N,K]^T (+bias)(tanh)(+resid) ----
// XOR-swizzled LDS (slot = kc ^ (row&7)); BK=64; tile 128x128, 4 waves 2x2.
// F32SRC: f32 inputs staged via regs->cvt->ds_write, classic sync loop (Ct).
// else:   global_load_lds dbuf + counted vmcnt(8) pipeline.
template<bool F32SRC, bool HAS_BIAS, bool TANH_ACT, bool RESID, bool OUT_BF16,
         int N, int K, int KREAL>
__device__ __forceinline__ void gemm_body(
    const void* __restrict__ Ap, const void* __restrict__ Btp,
    const float* __restrict__ bias, const float* __restrict__ resid,
    void* __restrict__ outp, int m0, int n0, unsigned char* smem)
{
    constexpr int NIT = K / 64;
    const int tid  = threadIdx.x;
    const int lane = tid & 63;
    const int wave = tid >> 6;          // 4 waves, 2x2
    const int wm   = wave & 1;
    const int wn   = wave >> 1;
    const int row16 = lane & 15;
    const int kq    = lane >> 4;        // 0..3

    f32x4 acc[4][4];
#pragma unroll
    for (int i = 0; i < 4; i++)
#pragma unroll
        for (int j = 0; j < 4; j++) acc[i][j] = (f32x4){0.f, 0.f, 0.f, 0.f};

    auto compute_tile = [&](const unsigned short* As, const unsigned short* Bs, bool full) {
        bf16x8 af[2][4], bg[2][4];
#pragma unroll
        for (int mi = 0; mi < 4; mi++) {
            const int r = wm * 64 + mi * 16 + row16;
            af[0][mi] = *(const bf16x8*)&As[r * 64 + (kq ^ (r & 7)) * 8];
            if (full) af[1][mi] = *(const bf16x8*)&As[r * 64 + ((4 + kq) ^ (r & 7)) * 8];
        }
#pragma unroll
        for (int ni = 0; ni < 4; ni++) {
            const int r = wn * 64 + ni * 16 + row16;
            bg[0][ni] = *(const bf16x8*)&Bs[r * 64 + (kq ^ (r & 7)) * 8];
            if (full) bg[1][ni] = *(const bf16x8*)&Bs[r * 64 + ((4 + kq) ^ (r & 7)) * 8];
        }
        __builtin_amdgcn_s_setprio(1);
#pragma unroll
        for (int mi = 0; mi < 4; mi++)
#pragma unroll
            for (int ni = 0; ni < 4; ni++)
                acc[mi][ni] = __builtin_amdgcn_mfma_f32_16x16x32_bf16(
                    af[0][mi], bg[0][ni], acc[mi][ni], 0, 0, 0);
        if (full) {
#pragma unroll
            for (int mi = 0; mi < 4; mi++)
#pragma unroll
                for (int ni = 0; ni < 4; ni++)
                    acc[mi][ni] = __builtin_amdgcn_mfma_f32_16x16x32_bf16(
                        af[1][mi], bg[1][ni], acc[mi][ni], 0, 0, 0);
        }
        __builtin_amdgcn_s_setprio(0);
    };

    if constexpr (F32SRC) {
        const float* A32 = (const float*)Ap;
        const float* B32 = (const float*)Btp;
        unsigned short* As = (unsigned short*)smem;
        unsigned short* Bs = As + 8192;
        for (int t = 0; t < NIT; ++t) {
#pragma unroll
            for (int i = 0; i < 4; ++i) {
                const int c = i * 256 + tid;            // 1024 chunks = 128 rows x 8 slots
                const int row = c >> 3, sl = c & 7;
                const int kcc = sl ^ (row & 7);
                const float* sa = A32 + (size_t)(m0 + row) * K + t * 64 + kcc * 8;
                *(bf16x8*)&As[row * 64 + sl * 8] = pack8(*(const float4*)sa, *(const float4*)(sa + 4));
                const float* sb = B32 + (size_t)(n0 + row) * K + t * 64 + kcc * 8;
                *(bf16x8*)&Bs[row * 64 + sl * 8] = pack8(*(const float4*)sb, *(const float4*)(sb + 4));
            }
            __syncthreads();
            compute_tile(As, Bs, true);
            __syncthreads();
        }
    } else {
        const __hip_bfloat16* A  = (const __hip_bfloat16*)Ap;
        const __hip_bfloat16* Bt = (const __hip_bfloat16*)Btp;
        const int rsub = lane >> 3;          // 0..7
        const int slot = lane & 7;           // 0..7
        const int kc   = slot ^ rsub;        // logical k-chunk this lane fetches
        const __hip_bfloat16* gA = A  + (size_t)(m0 + wave * 32 + rsub) * K + kc * 8;
        const __hip_bfloat16* gB = Bt + (size_t)(n0 + wave * 32 + rsub) * K + kc * 8;
        unsigned short* lA0 = (unsigned short*)smem + wave * 2048 + lane * 8;
        unsigned short* lB0 = lA0 + 8192;    // +16384 bytes within a buffer

        auto stage = [&](int t, int buf) {   // 8 global_load_lds for tile t -> buffer buf
            unsigned short* lA = lA0 + buf * 16384;   // buffer stride 32768 B
            unsigned short* lB = lB0 + buf * 16384;
            const __hip_bfloat16* a = gA + t * 64;
            const __hip_bfloat16* b = gB + t * 64;
#pragma unroll
            for (int i = 0; i < 4; i++) {
                async_cp16(a + (size_t)(8 * i) * K, lA + i * 512);
                async_cp16(b + (size_t)(8 * i) * K, lB + i * 512);
            }
            sched_fence();
        };

        stage(0, 0);
        if (NIT > 1) stage(1, 1);
#pragma unroll
        for (int t = 0; t < NIT; ++t) {
            if (t == NIT - 1) wait0_barrier(); else wait8_barrier();
            const unsigned short* As = (const unsigned short*)(smem + (t & 1) * 32768);
            const unsigned short* Bs = As + 8192;
            compute_tile(As, Bs, (t * 64 + 32 < KREAL));
            barrier_only();
            if (t + 2 < NIT) stage(t + 2, t & 1);
        }
    }

    // ---- epilogue: repack C-tile through LDS (stride 132: conflict-free) ----
    if (OUT_BF16) {
        unsigned short* rep = (unsigned short*)smem;   // 128 x 132 bf16 = 33792 B
#pragma unroll
        for (int ni = 0; ni < 4; ni++) {
            const int c = wn * 64 + ni * 16 + row16;
            float bcol = HAS_BIAS ? bias[n0 + c] : 0.f;
#pragma unroll
            for (int mi = 0; mi < 4; mi++)
#pragma unroll
                for (int r = 0; r < 4; r++) {
                    const int rr = wm * 64 + mi * 16 + kq * 4 + r;
                    float v = acc[mi][ni][r];
                    if (HAS_BIAS) v += bcol;
                    if (TANH_ACT) v = tanh_fast(v);
                    rep[rr * 132 + c] = f2bf_bits(v);
                }
        }
        __syncthreads();
#pragma unroll
        for (int p = 0; p < 8; p++) {
            const int lin = p * 256 + tid;     // 128 rows x 16 chunks of 8
            const int row = lin >> 4;
            const int c8  = lin & 15;
            const unsigned short* s = &rep[row * 132 + c8 * 8];   // 8B-aligned
            union { uint4 u; unsigned long long q[2]; } d;
            d.q[0] = *(const unsigned long long*)(s);
            d.q[1] = *(const unsigned long long*)(s + 4);
            *(uint4*)((__hip_bfloat16*)outp + (size_t)(m0 + row) * N + n0 + c8 * 8) = d.u;
        }
    } else {
        float* rep = (float*)smem;             // 64 x 132 f32 = 33792 B per half
#pragma unroll
        for (int h = 0; h < 2; h++) {
            if (wm == h) {
#pragma unroll
                for (int ni = 0; ni < 4; ni++) {
                    const int c = wn * 64 + ni * 16 + row16;
                    float bcol = HAS_BIAS ? bias[n0 + c] : 0.f;
#pragma unroll
                    for (int mi = 0; mi < 4; mi++)
#pragma unroll
                        for (int r = 0; r < 4; r++) {
                            const int rr = mi * 16 + kq * 4 + r;   // 0..63
                            float v = acc[mi][ni][r];
                            if (HAS_BIAS) v += bcol;
                            if (TANH_ACT) v = tanh_fast(v);
                            rep[rr * 132 + c] = v;
                        }
                }
            }
            __syncthreads();
#pragma unroll
            for (int p = 0; p < 8; p++) {
                const int lin = p * 256 + tid;   // 64 rows x 32 float4
                const int row = lin >> 5;
                const int c4  = lin & 31;
                float4 v = *(const float4*)&rep[row * 132 + c4 * 4];
                const int grow = m0 + h * 64 + row;
                if (RESID) {
                    float4 rv = *(const float4*)&resid[(size_t)grow * N + n0 + c4 * 4];
                    v.x += rv.x; v.y += rv.y; v.z += rv.z; v.w += rv.w;
                }
                *(float4*)((float*)outp + (size_t)grow * N + n0 + c4 * 4) = v;
            }
            __syncthreads();
        }
    }
}

// ---------- standalone GEMM (P and H) with XCD swizzle ----------
template<bool HAS_BIAS, bool TANH_ACT, bool RESID, bool OUT_BF16, int N, int K, int GX>
__global__ __launch_bounds__(256) void mfma_gemm(
    const __hip_bfloat16* __restrict__ A,
    const __hip_bfloat16* __restrict__ Bt,
    const float* __restrict__ bias,
    const float* __restrict__ resid,
    void* __restrict__ outp)
{
    __shared__ __align__(16) unsigned char smem[65536];
    int bx, by;
    {
        const int total = gridDim.x;
        const int per_xcd = total >> 3;
        if ((total & 7) == 0 && (per_xcd % GX) == 0) {
            int xcd = blockIdx.x & 7, idx = blockIdx.x >> 3;
            int lin = xcd * per_xcd + idx;
            by = lin / GX; bx = lin % GX;
        } else { by = blockIdx.x / GX; bx = blockIdx.x % GX; }
    }
    gemm_body<false, HAS_BIAS, TANH_ACT, RESID, OUT_BF16, N, K, K>(
        A, Bt, bias, resid, outp, by * 128, bx * 128, smem);
}

// ---------- T-GEMM v4: 320 blocks x 512 threads (8 waves = 2/SIMD) ----------
// Block owns 128 rows x full N=768. A staged once [4kt][128][64] = 64KB;
// B streamed per nt (64KB, single-buffered); rep 64x132 = 16.9KB. LDS 145KB.
// Per nt: stage B -> vmcnt(0)+barrier -> 4 kt compute (NO barriers) -> epilogue.
__global__ __launch_bounds__(512) void tgemm_kernel(
    const __hip_bfloat16* __restrict__ Eb,
    const __hip_bfloat16* __restrict__ W1Tb,
    const float* __restrict__ b1,
    __hip_bfloat16* __restrict__ Tb)
{
    __shared__ __align__(16) unsigned char smem[148480];
    unsigned short* Aall = (unsigned short*)smem;            // [4kt][128][64]
    unsigned short* Ball = (unsigned short*)(smem + 65536);  // [4kt][128][64]
    unsigned short* rep  = (unsigned short*)(smem + 131072); // [64][132]

    const int tid  = threadIdx.x;
    const int lane = tid & 63;
    const int wave = tid >> 6;     // 0..7
    const int wm   = wave & 3;     // m strip of 32
    const int wn   = wave >> 2;    // n strip of 64
    const int row16 = lane & 15;
    const int kq    = lane >> 4;

    const int blk = (blockIdx.x & 7) * 40 + (blockIdx.x >> 3);  // XCD-chunked, 320=8x40
    const int m0  = blk * 128;

    // ---- stage A once: 4 kt tiles, 2 chunks/thread each ----
#pragma unroll
    for (int kt = 0; kt < 4; ++kt)
#pragma unroll
        for (int i = 0; i < 2; ++i) {
            const int c = i * 512 + tid;            // 1024 chunks: row 0..127, slot 0..7
            const int row = c >> 3, sl = c & 7;
            const int kcc = sl ^ (row & 7);
            async_cp16(Eb + (size_t)(m0 + row) * 256 + kt * 64 + kcc * 8,
                       Aall + kt * 8192 + c * 8);
        }
    sched_fence();

    for (int nt = 0; nt < 6; ++nt) {
        // ---- stage B for this nt (4 kt tiles) ----
#pragma unroll
        for (int kt = 0; kt < 4; ++kt)
#pragma unroll
            for (int i = 0; i < 2; ++i) {
                const int c = i * 512 + tid;
                const int row = c >> 3, sl = c & 7;
                const int kcc = sl ^ (row & 7);
                async_cp16(W1Tb + (size_t)(nt * 128 + row) * 256 + kt * 64 + kcc * 8,
                           Ball + kt * 8192 + c * 8);
            }
        sched_fence();
        wait0_barrier();     // B (and A on nt=0) resident; prior stores drained

        f32x4 acc[2][4];
#pragma unroll
        for (int i = 0; i < 2; i++)
#pragma unroll
            for (int j = 0; j < 4; j++) acc[i][j] = (f32x4){0.f, 0.f, 0.f, 0.f};

#pragma unroll
        for (int kt = 0; kt < 4; ++kt) {
            const unsigned short* As = Aall + kt * 8192;
            const unsigned short* Bs = Ball + kt * 8192;
            const bool full = (kt < 3);              // KREAL=224: kt=3 only kh=0

            bf16x8 af[2][2], bg[2][4];
#pragma unroll
            for (int mi = 0; mi < 2; mi++) {
                const int r = wm * 32 + mi * 16 + row16;
                af[0][mi] = *(const bf16x8*)&As[r * 64 + (kq ^ (r & 7)) * 8];
                if (full) af[1][mi] = *(const bf16x8*)&As[r * 64 + ((4 + kq) ^ (r & 7)) * 8];
            }
#pragma unroll
            for (int ni = 0; ni < 4; ni++) {
                const int r = wn * 64 + ni * 16 + row16;
                bg[0][ni] = *(const bf16x8*)&Bs[r * 64 + (kq ^ (r & 7)) * 8];
                if (full) bg[1][ni] = *(const bf16x8*)&Bs[r * 64 + ((4 + kq) ^ (r & 7)) * 8];
            }
            __builtin_amdgcn_s_setprio(1);
#pragma unroll
            for (int mi = 0; mi < 2; mi++)
#pragma unroll
                for (int ni = 0; ni < 4; ni++)
                    acc[mi][ni] = __builtin_amdgcn_mfma_f32_16x16x32_bf16(
                        af[0][mi], bg[0][ni], acc[mi][ni], 0, 0, 0);
            if (full) {
#pragma unroll
                for (int mi = 0; mi < 2; mi++)
#pragma unroll
                    for (int ni = 0; ni < 4; ni++)
                        acc[mi][ni] = __builtin_amdgcn_mfma_f32_16x16x32_bf16(
                            af[1][mi], bg[1][ni], acc[mi][ni], 0, 0, 0);
            }
            __builtin_amdgcn_s_setprio(0);
        }
        barrier_only();      // all waves done reading B before next nt / rep reuse

        // ---- epilogue: two 64-row passes through rep ----
#pragma unroll
        for (int h = 0; h < 2; ++h) {
            if ((wm >> 1) == h) {                    // waves wm={2h,2h+1} own these rows
#pragma unroll
                for (int ni = 0; ni < 4; ni++) {
                    const int c = wn * 64 + ni * 16 + row16;
                    const float bcol = b1[nt * 128 + c];
#pragma unroll
                    for (int mi = 0; mi < 2; mi++)
#pragma unroll
                        for (int r = 0; r < 4; r++) {
                            const int rr = (wm & 1) * 32 + mi * 16 + kq * 4 + r;
                            rep[rr * 132 + c] = f2bf_bits(tanh_fast(acc[mi][ni][r] + bcol));
                        }
                }
            }
            lgkm_barrier();
#pragma unroll
            for (int p = 0; p < 2; p++) {
                const int lin = p * 512 + tid;       // 64 rows x 16 chunks of 8
                const int row = lin >> 4;
                const int c8  = lin & 15;
                const unsigned short* s = &rep[row * 132 + c8 * 8];
                union { uint4 u; unsigned long long q[2]; } d;
                d.q[0] = *(const unsigned long long*)(s);
                d.q[1] = *(const unsigned long long*)(s + 4);
                *(uint4*)(Tb + (size_t)(m0 + h * 64 + row) * 768 + nt * 128 + c8 * 8) = d.u;
            }
            barrier_only();                          // rep reads done before next pass
        }
    }
}

// ---------- fused prep: Ct FIRST, transposes, then fat streaming blocks ----------
__global__ __launch_bounds__(256) void prep_kernel(
    const float* __restrict__ x,  __hip_bfloat16* __restrict__ xb,
    const float* __restrict__ w2,
    const float* __restrict__ aw,
    const float* __restrict__ E,  __hip_bfloat16* __restrict__ Eb,
    const float* __restrict__ W1, __hip_bfloat16* __restrict__ W1Tb,
    __hip_bfloat16* __restrict__ W2Tb,
    __hip_bfloat16* __restrict__ Ctb)
{
    __shared__ __align__(16) unsigned char smem[33792];
    float (*tile)[33] = (float(*)[33])smem;
    const int b = blockIdx.x, tid = threadIdx.x;
    if (b < 36) {                                     // Ct = W2 @ attn_W^T from f32
        gemm_body<true, false, false, false, true, 768, 768, 768>(
            w2, aw, nullptr, nullptr, Ctb, (b / 6) * 128, (b % 6) * 128, smem);
    } else if (b < 804) {                             // transposes, (32,8) tiles
        const float* in; __hip_bfloat16* outb; int R, C, Rpad, t;
        if (b < 228) { t = b - 36;  in = W1; outb = W1Tb; R = 200; C = 768; Rpad = 256; }
        else         { t = b - 228; in = w2; outb = W2Tb; R = 768; C = 768; Rpad = 768; }
        const int c0 = (t % 24) * 32, r0 = (t / 24) * 32;
        const int xx = tid & 31, yy = tid >> 5;       // (32,8)
#pragma unroll
        for (int i = 0; i < 32; i += 8) {
            int r = r0 + yy + i;
            tile[yy + i][xx] = (r < R) ? in[(size_t)r * C + c0 + xx] : 0.f;
        }
        __syncthreads();
#pragma unroll
        for (int i = 0; i < 32; i += 8)
            outb[(size_t)(c0 + yy + i) * Rpad + r0 + xx] = __float2bfloat16(tile[xx][yy + i]);
    } else if (b < 1572) {                            // x f32->bf16, 8 float4/thread
        const long long base = (long long)(b - 804) * 2048 + tid;   // in float4 units
        float4 v[8];
#pragma unroll
        for (int j = 0; j < 8; j++) v[j] = ((const float4*)x)[base + j * 256];
#pragma unroll
        for (int j = 0; j < 8; j++)
            ((ushort4*)xb)[base + j * 256] =
                make_ushort4(f2bf_bits(v[j].x), f2bf_bits(v[j].y), f2bf_bits(v[j].z), f2bf_bits(v[j].w));
    } else {                                          // E [40960,200] -> Eb [40960,256]
        const int lane = tid & 63, wave = tid >> 6;
        const long long r0 = (long long)(b - 1572) * 32 + wave * 8;  // 8 rows per wave
        const int k = lane * 4;
        float4 v[8];
#pragma unroll
        for (int j = 0; j < 8; j++) {
            v[j] = make_float4(0.f, 0.f, 0.f, 0.f);
            if (k < 200) v[j] = *(const float4*)&E[(r0 + j) * 200 + k];   // k<=196 in-bounds
        }
#pragma unroll
        for (int j = 0; j < 8; j++)
            *(ushort4*)&Eb[(r0 + j) * 256 + k] =
                make_ushort4(f2bf_bits(v[j].x), f2bf_bits(v[j].y), f2bf_bits(v[j].z), f2bf_bits(v[j].w));
    }
}

// ---------- attention: wave per (b,s) row; P aliases S ----------
__global__ __launch_bounds__(256) void attn_kernel(
    const __hip_bfloat16* __restrict__ T,
    const __hip_bfloat16* P,
    const int* __restrict__ mask,
    __hip_bfloat16* S)
{
    const int lane = threadIdx.x & 63;
    const int wave = threadIdx.x >> 6;
    const int r    = blockIdx.x * 4 + wave;
    const int base = lane * 12;

    float pv[12];
    {
        const ushort4* pp = (const ushort4*)((const unsigned short*)P + (size_t)r * 768 + base);
        ushort4 u0 = pp[0], u1 = pp[1], u2 = pp[2];
        unsigned short us[12] = {u0.x,u0.y,u0.z,u0.w, u1.x,u1.y,u1.z,u1.w, u2.x,u2.y,u2.z,u2.w};
#pragma unroll
        for (int j = 0; j < 12; j++) pv[j] = bf_bits2f(us[j]);
    }
    float tv[5][12], part[5];
#pragma unroll
    for (int w = 0; w < 5; w++) {
        const ushort4* tp = (const ushort4*)((const unsigned short*)T + ((size_t)r * 5 + w) * 768 + base);
        ushort4 u0 = tp[0], u1 = tp[1], u2 = tp[2];
        unsigned short us[12] = {u0.x,u0.y,u0.z,u0.w, u1.x,u1.y,u1.z,u1.w, u2.x,u2.y,u2.z,u2.w};
        float s = 0.f;
#pragma unroll
        for (int j = 0; j < 12; j++) { tv[w][j] = bf_bits2f(us[j]); s += tv[w][j] * pv[j]; }
        part[w] = s;
    }
#pragma unroll
    for (int off = 32; off > 0; off >>= 1)
#pragma unroll
        for (int w = 0; w < 5; w++)
            part[w] += __shfl_xor(part[w], off, 64);

    float logit[5], mx = -1e30f;
#pragma unroll
    for (int w = 0; w < 5; w++) {
        float m = (float)mask[(size_t)r * 5 + w];
        logit[w] = part[w] - 10000.0f * (1.0f - m);
        mx = fmaxf(mx, logit[w]);
    }
    float se = 0.f;
#pragma unroll
    for (int w = 0; w < 5; w++) { logit[w] = expf(logit[w] - mx); se += logit[w]; }
    const float inv = 1.0f / se;

    unsigned short os[12];
#pragma unroll
    for (int j = 0; j < 12; j++) {
        float s = 0.f;
#pragma unroll
        for (int w = 0; w < 5; w++) s += logit[w] * tv[w][j];
        os[j] = f2bf_bits(s * inv);
    }
    ushort4* sp = (ushort4*)((unsigned short*)S + (size_t)r * 768 + base);
    sp[0] = make_ushort4(os[0], os[1], os[2],  os[3]);
    sp[1] = make_ushort4(os[4], os[5], os[6],  os[7]);
    sp[2] = make_ushort4(os[8], os[9], os[10], os[11]);
}

// ---------- LayerNorm over H=768, wave per row ----------
__global__ __launch_bounds__(256) void ln_kernel(
    const float* __restrict__ Hbuf, const float* __restrict__ gamma,
    const float* __restrict__ beta, float* __restrict__ out)
{
    const int lane = threadIdx.x & 63;
    const int wave = threadIdx.x >> 6;
    const int r    = blockIdx.x * 4 + wave;
    const float* hr = Hbuf + (size_t)r * 768 + lane * 12;

    float v[12];
    {
        float4 a = *(const float4*)(hr);
        float4 b = *(const float4*)(hr + 4);
        float4 c = *(const float4*)(hr + 8);
        v[0]=a.x; v[1]=a.y; v[2]=a.z; v[3]=a.w;
        v[4]=b.x; v[5]=b.y; v[6]=b.z; v[7]=b.w;
        v[8]=c.x; v[9]=c.y; v[10]=c.z; v[11]=c.w;
    }
    float s = 0.f;
#pragma unroll
    for (int j = 0; j < 12; j++) s += v[j];
#pragma unroll
    for (int off = 32; off > 0; off >>= 1) s += __shfl_xor(s, off, 64);
    const float mu = s * (1.f / 768.f);
    float vs = 0.f;
#pragma unroll
    for (int j = 0; j < 12; j++) { float d = v[j] - mu; vs += d * d; }
#pragma unroll
    for (int off = 32; off > 0; off >>= 1) vs += __shfl_xor(vs, off, 64);
    const float rs = rsqrtf(vs * (1.f / 768.f) + 1e-12f);

    float o[12];
#pragma unroll
    for (int j = 0; j < 12; j++) {
        int h = lane * 12 + j;
        o[j] = (v[j] - mu) * rs * gamma[h] + beta[h];
    }
    float* orow = out + (size_t)r * 768 + lane * 12;
    *(float4*)(orow)     = make_float4(o[0], o[1], o[2],  o[3]);
    *(float4*)(orow + 4) = make_float4(o[4], o[5], o[6],  o[7]);
    *(float4*)(orow + 8) = make_float4(o[8], o[9], o[10], o[11]);
}

extern "C" void kernel_launch(void* const* d_in, const int* in_sizes, int n_in,
                              void* d_out, int out_size, void* d_ws, size_t ws_size,
                              hipStream_t stream)
{
    const float* x      = (const float*)d_in[0];
    const float* E      = (const float*)d_in[1];
    const int*   mask   = (const int*)d_in[2];
    const float* W1     = (const float*)d_in[3];
    const float* b1     = (const float*)d_in[4];
    const float* W2     = (const float*)d_in[5];
    const float* b2     = (const float*)d_in[6];
    const float* attn_W = (const float*)d_in[7];
    const float* gamma  = (const float*)d_in[8];
    const float* beta   = (const float*)d_in[9];
    float* out = (float*)d_out;

    const int BS = 8192, H = 768, M1 = 40960, KP = 256;

    char* p = (char*)d_ws;
    auto alloc = [&](size_t bytes) { char* q = p; p += (bytes + 255) & ~(size_t)255; return q; };
    __hip_bfloat16* xb    = (__hip_bfloat16*)alloc((size_t)BS * H * 2);    // 12.58 MB
    __hip_bfloat16* W2Tb  = (__hip_bfloat16*)alloc((size_t)H * H * 2);
    __hip_bfloat16* Ctb   = (__hip_bfloat16*)alloc((size_t)H * H * 2);
    __hip_bfloat16* W1Tb  = (__hip_bfloat16*)alloc((size_t)H * KP * 2);
    __hip_bfloat16* Tb    = (__hip_bfloat16*)alloc((size_t)M1 * H * 2);    // 62.92 MB
    __hip_bfloat16* Eb    = (__hip_bfloat16*)alloc((size_t)M1 * KP * 2);   // 20.97 MB
    float* Hb = (float*)Tb;              // alias: Tb dead after attn
    __hip_bfloat16* Pb = Eb;             // alias: Eb dead after T-GEMM
    __hip_bfloat16* Sb = Pb;             // alias: same-wave read-then-write

    // 1) prep: Ct (36, FIRST) + W1T (192) + W2T (576) + x cvt (768 fat) + E pad (1280 fat)
    prep_kernel<<<2852, 256, 0, stream>>>(x, xb, W2, attn_W, E, Eb, W1, W1Tb, W2Tb, Ctb);

    // 2) T = tanh(Eb @ W1 + b1)  [320 blocks x 512 threads, A-resident]
    tgemm_kernel<<<320, 512, 0, stream>>>(Eb, W1Tb, b1, Tb);

    // 3) P = x @ Ct^T  (384 blocks, XCD-swizzled; Pb aliases Eb -- dead after T)
    mfma_gemm<false, false, false, true, 768, 768, 6><<<384, 256, 0, stream>>>(
        xb, Ctb, nullptr, nullptr, Pb);

    // 4) attention -> S
    attn_kernel<<<BS / 4, 256, 0, stream>>>(Tb, Pb, mask, Sb);

    // 5) H = x + S @ W2 + b2
    mfma_gemm<true, false, true, false, 768, 768, 6><<<384, 256, 0, stream>>>(
        Sb, W2Tb, b2, x, Hb);

    // 6) out = LN(H)*gamma + beta
    ln_kernel<<<BS / 4, 256, 0, stream>>>(Hb, gamma, beta, out);
}

// Round 9
// 211.660 us; speedup vs baseline: 1.2647x; 1.2647x over previous
//
#include <hip/hip_runtime.h>
#include <hip/hip_bf16.h>
#include <math.h>

// Problem dims: B=16,S=512,W=5,D=200,H=768  (BS=8192 rows, M1=40960 word-rows)
// Math: Ct = W2@attn_W^T; T = tanh(E@W1+b1); P = x@Ct^T; alpha = softmax(T_w.P+mask)
//       S = sum_w alpha_w T_w; H = x + S@W2 + b2; out = LN(H)*gamma+beta
// R18: re-anchor on R2 (verified 211.8us best). tgemm series data: simple
//      1920-block dbuf = 43us; every bigger-LDS/persistent variant regressed
//      (57/65/75us) -- 128^2 tile at K=256 is ~L2-staging-bound (57 FLOP/byte
//      needs 43TB/s > 34.5 L2 ceiling), so ~43us stands. ONE isolated change
//      vs R2: prep streaming re-packed into FAT blocks (8 independent float4
//      loads batched per thread, 2960 blocks vs 18304) -- R4 measured the thin
//      version latency-chained at 1.3TB/s. Everything else R2-verbatim.

typedef __attribute__((ext_vector_type(8))) short bf16x8;
typedef __attribute__((ext_vector_type(4))) float f32x4;

__device__ __forceinline__ unsigned short f2bf_bits(float f) {
    __hip_bfloat16 h = __float2bfloat16(f);
    return *reinterpret_cast<unsigned short*>(&h);
}
__device__ __forceinline__ float bf_bits2f(unsigned short u) {
    union { unsigned int i; float f; } v; v.i = ((unsigned int)u) << 16; return v.f;
}
__device__ __forceinline__ float tanh_fast(float x) {
    float xc = fminf(fmaxf(x, -9.f), 9.f);
    float t  = __expf(2.f * xc);
    return (t - 1.f) * __builtin_amdgcn_rcpf(t + 1.f);
}

__device__ __forceinline__ void async_cp16(const void* g, void* lds) {
#if __has_builtin(__builtin_amdgcn_global_load_lds)
    auto gp = (const __attribute__((address_space(1))) unsigned int*)g;
    auto lp = (__attribute__((address_space(3))) unsigned int*)lds;
    __builtin_amdgcn_global_load_lds(gp, lp, 16, 0, 0);
#else
    *(uint4*)lds = *(const uint4*)g;
#endif
}

// compiler-level scheduling fence: keeps stage() issue groups in program order
// so the counted vmcnt math stays valid (buf0's 8 loads strictly older than buf1's).
__device__ __forceinline__ void sched_fence()  { asm volatile("" ::: "memory"); }
__device__ __forceinline__ void wait8_barrier(){ asm volatile("s_waitcnt vmcnt(8)\ns_barrier" ::: "memory"); }
__device__ __forceinline__ void wait0_barrier(){ asm volatile("s_waitcnt vmcnt(0)\ns_barrier" ::: "memory"); }
__device__ __forceinline__ void barrier_only() { asm volatile("s_barrier" ::: "memory"); }

// ---------- MFMA bf16 GEMM body: D = A[M,K] @ Bt[N,K]^T (+bias)(tanh)(+resid) ----
// XOR-swizzled LDS (slot = kc ^ (row&7)); BK=64; K%64==0; KREAL = valid k cols.
// Double-buffered: tile t lives in buffer t&1 (32KB each); stage(t+2) issued after
// the compute barrier of iter t; consumed after wait8_barrier of iter t+2.
template<bool HAS_BIAS, bool TANH_ACT, bool RESID, bool OUT_BF16, int N, int K, int KREAL>
__device__ __forceinline__ void gemm_body(
    const __hip_bfloat16* __restrict__ A,
    const __hip_bfloat16* __restrict__ Bt,
    const float* __restrict__ bias,
    const float* __restrict__ resid,
    void* __restrict__ outp,
    int m0, int n0, unsigned char* smem)
{
    constexpr int NIT = K / 64;

    const int tid  = threadIdx.x;
    const int lane = tid & 63;
    const int wave = tid >> 6;          // 4 waves, 2x2
    const int wm   = wave & 1;
    const int wn   = wave >> 1;

    const int rsub = lane >> 3;          // 0..7
    const int slot = lane & 7;           // 0..7
    const int kc   = slot ^ rsub;        // logical k-chunk this lane fetches
    const __hip_bfloat16* gA = A  + (size_t)(m0 + wave * 32 + rsub) * K + kc * 8;
    const __hip_bfloat16* gB = Bt + (size_t)(n0 + wave * 32 + rsub) * K + kc * 8;
    unsigned short* lA0 = (unsigned short*)smem + wave * 2048 + lane * 8;
    unsigned short* lB0 = lA0 + 8192;    // +16384 bytes within a buffer

    const int row16 = lane & 15;
    const int kq    = lane >> 4;         // 0..3

    f32x4 acc[4][4];
#pragma unroll
    for (int i = 0; i < 4; i++)
#pragma unroll
        for (int j = 0; j < 4; j++) acc[i][j] = (f32x4){0.f, 0.f, 0.f, 0.f};

    auto stage = [&](int t) {            // issue 8 global_load_lds for tile t
        unsigned short* lA = lA0 + (t & 1) * 16384;   // buffer stride 32768 B
        unsigned short* lB = lB0 + (t & 1) * 16384;
        const __hip_bfloat16* a = gA + t * 64;
        const __hip_bfloat16* b = gB + t * 64;
#pragma unroll
        for (int i = 0; i < 4; i++) {
            async_cp16(a + (size_t)(8 * i) * K, lA + i * 512);
            async_cp16(b + (size_t)(8 * i) * K, lB + i * 512);
        }
        sched_fence();
    };

    stage(0);
    if (NIT > 1) stage(1);

#pragma unroll
    for (int t = 0; t < NIT; ++t) {
        // wait for tile t's 8 loads (tile t+1's 8 may remain in flight), then sync
        if (t == NIT - 1) wait0_barrier(); else wait8_barrier();

        const unsigned short* As = (const unsigned short*)(smem + (t & 1) * 32768);
        const unsigned short* Bs = As + 8192;
        const bool full = (t * 64 + 32 < KREAL);   // compile-time per unrolled iter

        bf16x8 af[2][4], bg[2][4];
#pragma unroll
        for (int mi = 0; mi < 4; mi++) {
            const int r = wm * 64 + mi * 16 + row16;
            af[0][mi] = *(const bf16x8*)&As[r * 64 + (kq ^ (r & 7)) * 8];
            if (full) af[1][mi] = *(const bf16x8*)&As[r * 64 + ((4 + kq) ^ (r & 7)) * 8];
        }
#pragma unroll
        for (int ni = 0; ni < 4; ni++) {
            const int r = wn * 64 + ni * 16 + row16;
            bg[0][ni] = *(const bf16x8*)&Bs[r * 64 + (kq ^ (r & 7)) * 8];
            if (full) bg[1][ni] = *(const bf16x8*)&Bs[r * 64 + ((4 + kq) ^ (r & 7)) * 8];
        }
#pragma unroll
        for (int mi = 0; mi < 4; mi++)
#pragma unroll
            for (int ni = 0; ni < 4; ni++)
                acc[mi][ni] = __builtin_amdgcn_mfma_f32_16x16x32_bf16(
                    af[0][mi], bg[0][ni], acc[mi][ni], 0, 0, 0);
        if (full) {
#pragma unroll
            for (int mi = 0; mi < 4; mi++)
#pragma unroll
                for (int ni = 0; ni < 4; ni++)
                    acc[mi][ni] = __builtin_amdgcn_mfma_f32_16x16x32_bf16(
                        af[1][mi], bg[1][ni], acc[mi][ni], 0, 0, 0);
        }
        // all waves done READING buffer t&1 before tile t+2 overwrites it
        barrier_only();
        if (t + 2 < NIT) stage(t + 2);
    }

    // ---- epilogue: repack C-tile through LDS (stride 132: conflict-free) ----
    if (OUT_BF16) {
        unsigned short* rep = (unsigned short*)smem;   // 128 x 132 bf16 = 33792 B
#pragma unroll
        for (int ni = 0; ni < 4; ni++) {
            const int c = wn * 64 + ni * 16 + row16;
            float bcol = HAS_BIAS ? bias[n0 + c] : 0.f;
#pragma unroll
            for (int mi = 0; mi < 4; mi++)
#pragma unroll
                for (int r = 0; r < 4; r++) {
                    const int rr = wm * 64 + mi * 16 + kq * 4 + r;
                    float v = acc[mi][ni][r];
                    if (HAS_BIAS) v += bcol;
                    if (TANH_ACT) v = tanh_fast(v);
                    rep[rr * 132 + c] = f2bf_bits(v);
                }
        }
        __syncthreads();
#pragma unroll
        for (int p = 0; p < 8; p++) {
            const int lin = p * 256 + tid;     // 128 rows x 16 chunks of 8
            const int row = lin >> 4;
            const int c8  = lin & 15;
            const unsigned short* s = &rep[row * 132 + c8 * 8];   // 8B-aligned
            union { uint4 u; unsigned long long q[2]; } d;
            d.q[0] = *(const unsigned long long*)(s);
            d.q[1] = *(const unsigned long long*)(s + 4);
            *(uint4*)((__hip_bfloat16*)outp + (size_t)(m0 + row) * N + n0 + c8 * 8) = d.u;
        }
    } else {
        float* rep = (float*)smem;             // 64 x 132 f32 = 33792 B per half
#pragma unroll
        for (int h = 0; h < 2; h++) {
            if (wm == h) {
#pragma unroll
                for (int ni = 0; ni < 4; ni++) {
                    const int c = wn * 64 + ni * 16 + row16;
                    float bcol = HAS_BIAS ? bias[n0 + c] : 0.f;
#pragma unroll
                    for (int mi = 0; mi < 4; mi++)
#pragma unroll
                        for (int r = 0; r < 4; r++) {
                            const int rr = mi * 16 + kq * 4 + r;   // 0..63
                            float v = acc[mi][ni][r];
                            if (HAS_BIAS) v += bcol;
                            if (TANH_ACT) v = tanh_fast(v);
                            rep[rr * 132 + c] = v;
                        }
                }
            }
            __syncthreads();
#pragma unroll
            for (int p = 0; p < 8; p++) {
                const int lin = p * 256 + tid;   // 64 rows x 32 float4
                const int row = lin >> 5;
                const int c4  = lin & 31;
                float4 v = *(const float4*)&rep[row * 132 + c4 * 4];  // 528B rows, 16B-aligned
                const int grow = m0 + h * 64 + row;
                if (RESID) {
                    float4 rv = *(const float4*)&resid[(size_t)grow * N + n0 + c4 * 4];
                    v.x += rv.x; v.y += rv.y; v.z += rv.z; v.w += rv.w;
                }
                *(float4*)((float*)outp + (size_t)grow * N + n0 + c4 * 4) = v;
            }
            __syncthreads();
        }
    }
}

// ---------- standalone GEMM (P and H) with XCD swizzle ----------
template<bool HAS_BIAS, bool TANH_ACT, bool RESID, bool OUT_BF16, int N, int K, int GX>
__global__ __launch_bounds__(256) void mfma_gemm(
    const __hip_bfloat16* __restrict__ A,
    const __hip_bfloat16* __restrict__ Bt,
    const float* __restrict__ bias,
    const float* __restrict__ resid,
    void* __restrict__ outp)
{
    __shared__ __align__(16) unsigned char smem[65536];
    int bx, by;
    {
        const int total = gridDim.x;
        const int per_xcd = total >> 3;
        if ((total & 7) == 0 && (per_xcd % GX) == 0) {
            int xcd = blockIdx.x & 7, idx = blockIdx.x >> 3;
            int lin = xcd * per_xcd + idx;
            by = lin / GX; bx = lin % GX;
        } else { by = blockIdx.x / GX; bx = blockIdx.x % GX; }
    }
    gemm_body<HAS_BIAS, TANH_ACT, RESID, OUT_BF16, N, K, K>(
        A, Bt, bias, resid, outp, by * 128, bx * 128, smem);
}

// ---------- fused Ct-GEMM (blocks 0..35, long, launched FIRST) + T-GEMM ----------
__global__ __launch_bounds__(256) void tct_kernel(
    const __hip_bfloat16* __restrict__ Eb,   const __hip_bfloat16* __restrict__ W1Tb,
    const float* __restrict__ b1,            __hip_bfloat16* __restrict__ Tb,
    const __hip_bfloat16* __restrict__ W2b,  const __hip_bfloat16* __restrict__ attnb,
    __hip_bfloat16* __restrict__ Ctb)
{
    __shared__ __align__(16) unsigned char smem[65536];
    if (blockIdx.x < 36) {                   // Ct = W2 @ attn_W^T (12 K-iters)
        const int id = blockIdx.x;
        gemm_body<false, false, false, true, 768, 768, 768>(
            W2b, attnb, nullptr, nullptr, Ctb, (id / 6) * 128, (id % 6) * 128, smem);
    } else {
        // XCD swizzle over 1920 blocks, GX=6 (240 per XCD, 240%6==0)
        const int idq = blockIdx.x - 36;     // 0..1919
        const int xcd = idq & 7, idx = idq >> 3;
        const int lin = xcd * 240 + idx;
        gemm_body<true, true, false, true, 768, 256, 224>(
            Eb, W1Tb, b1, nullptr, Tb, (lin / 6) * 128, (lin % 6) * 128, smem);
    }
}

// ---------- fat prep: transposes + batched-ILP streaming cvts ----------
// 0..191:   W1 transpose -> W1Tb [768,256-pad]
// 192..767: W2 transpose -> W2Tb [768,768]
// 768..839: W2 cvt fat (72 blocks, 8 float4/thread)
// 840..911: attn_W cvt fat (72)
// 912..1679: x cvt fat (768)
// 1680..2959: E pad fat (1280, 32 rows/block, 8 independent row-loads/wave batched)
__global__ __launch_bounds__(256) void prep_kernel(
    const float* __restrict__ x,  __hip_bfloat16* __restrict__ xb,
    const float* __restrict__ w2, __hip_bfloat16* __restrict__ w2b,
    const float* __restrict__ aw, __hip_bfloat16* __restrict__ awb,
    const float* __restrict__ E,  __hip_bfloat16* __restrict__ Eb,
    const float* __restrict__ W1, __hip_bfloat16* __restrict__ W1Tb,
    __hip_bfloat16* __restrict__ W2Tb)
{
    __shared__ float tile[32][33];
    const int b = blockIdx.x, tid = threadIdx.x;
    if (b < 768) {                                    // transposes, (32,8) tiles
        const float* in; __hip_bfloat16* outb; int R, C, Rpad, t;
        if (b < 192) { t = b;       in = W1; outb = W1Tb; R = 200; C = 768; Rpad = 256; }
        else         { t = b - 192; in = w2; outb = W2Tb; R = 768; C = 768; Rpad = 768; }
        const int c0 = (t % 24) * 32, r0 = (t / 24) * 32;
        const int xx = tid & 31, yy = tid >> 5;       // (32,8)
#pragma unroll
        for (int i = 0; i < 32; i += 8) {
            int r = r0 + yy + i;
            tile[yy + i][xx] = (r < R) ? in[(size_t)r * C + c0 + xx] : 0.f;
        }
        __syncthreads();
#pragma unroll
        for (int i = 0; i < 32; i += 8)
            outb[(size_t)(c0 + yy + i) * Rpad + r0 + xx] = __float2bfloat16(tile[xx][yy + i]);
    } else if (b < 912) {                             // W2 / attn_W cvt, 8 float4/thread
        const float* src; __hip_bfloat16* dst; long long base;
        if (b < 840) { src = w2; dst = w2b; base = (long long)(b - 768) * 2048 + tid; }
        else         { src = aw; dst = awb; base = (long long)(b - 840) * 2048 + tid; }
        float4 v[8];
#pragma unroll
        for (int j = 0; j < 8; j++) v[j] = ((const float4*)src)[base + j * 256];
#pragma unroll
        for (int j = 0; j < 8; j++)
            ((ushort4*)dst)[base + j * 256] =
                make_ushort4(f2bf_bits(v[j].x), f2bf_bits(v[j].y), f2bf_bits(v[j].z), f2bf_bits(v[j].w));
    } else if (b < 1680) {                            // x cvt, 8 float4/thread
        const long long base = (long long)(b - 912) * 2048 + tid;
        float4 v[8];
#pragma unroll
        for (int j = 0; j < 8; j++) v[j] = ((const float4*)x)[base + j * 256];
#pragma unroll
        for (int j = 0; j < 8; j++)
            ((ushort4*)xb)[base + j * 256] =
                make_ushort4(f2bf_bits(v[j].x), f2bf_bits(v[j].y), f2bf_bits(v[j].z), f2bf_bits(v[j].w));
    } else {                                          // E [40960,200] -> Eb [40960,256]
        const int lane = tid & 63, wave = tid >> 6;
        const long long r0 = (long long)(b - 1680) * 32 + wave * 8;  // 8 rows per wave
        const int k = lane * 4;
        float4 v[8];
#pragma unroll
        for (int j = 0; j < 8; j++) {
            v[j] = make_float4(0.f, 0.f, 0.f, 0.f);
            if (k < 200) v[j] = *(const float4*)&E[(r0 + j) * 200 + k];   // k<=196 in-bounds
        }
#pragma unroll
        for (int j = 0; j < 8; j++)
            *(ushort4*)&Eb[(r0 + j) * 256 + k] =
                make_ushort4(f2bf_bits(v[j].x), f2bf_bits(v[j].y), f2bf_bits(v[j].z), f2bf_bits(v[j].w));
    }
}

// ---------- attention: wave per (b,s) row; P aliases S ----------
__global__ __launch_bounds__(256) void attn_kernel(
    const __hip_bfloat16* __restrict__ T,
    const __hip_bfloat16* P,
    const int* __restrict__ mask,
    __hip_bfloat16* S)
{
    const int lane = threadIdx.x & 63;
    const int wave = threadIdx.x >> 6;
    const int r    = blockIdx.x * 4 + wave;
    const int base = lane * 12;

    float pv[12];
    {
        const ushort4* pp = (const ushort4*)((const unsigned short*)P + (size_t)r * 768 + base);
        ushort4 u0 = pp[0], u1 = pp[1], u2 = pp[2];
        unsigned short us[12] = {u0.x,u0.y,u0.z,u0.w, u1.x,u1.y,u1.z,u1.w, u2.x,u2.y,u2.z,u2.w};
#pragma unroll
        for (int j = 0; j < 12; j++) pv[j] = bf_bits2f(us[j]);
    }
    float tv[5][12], part[5];
#pragma unroll
    for (int w = 0; w < 5; w++) {
        const ushort4* tp = (const ushort4*)((const unsigned short*)T + ((size_t)r * 5 + w) * 768 + base);
        ushort4 u0 = tp[0], u1 = tp[1], u2 = tp[2];
        unsigned short us[12] = {u0.x,u0.y,u0.z,u0.w, u1.x,u1.y,u1.z,u1.w, u2.x,u2.y,u2.z,u2.w};
        float s = 0.f;
#pragma unroll
        for (int j = 0; j < 12; j++) { tv[w][j] = bf_bits2f(us[j]); s += tv[w][j] * pv[j]; }
        part[w] = s;
    }
#pragma unroll
    for (int off = 32; off > 0; off >>= 1)
#pragma unroll
        for (int w = 0; w < 5; w++)
            part[w] += __shfl_xor(part[w], off, 64);

    float logit[5], mx = -1e30f;
#pragma unroll
    for (int w = 0; w < 5; w++) {
        float m = (float)mask[(size_t)r * 5 + w];
        logit[w] = part[w] - 10000.0f * (1.0f - m);
        mx = fmaxf(mx, logit[w]);
    }
    float se = 0.f;
#pragma unroll
    for (int w = 0; w < 5; w++) { logit[w] = expf(logit[w] - mx); se += logit[w]; }
    const float inv = 1.0f / se;

    unsigned short os[12];
#pragma unroll
    for (int j = 0; j < 12; j++) {
        float s = 0.f;
#pragma unroll
        for (int w = 0; w < 5; w++) s += logit[w] * tv[w][j];
        os[j] = f2bf_bits(s * inv);
    }
    ushort4* sp = (ushort4*)((unsigned short*)S + (size_t)r * 768 + base);
    sp[0] = make_ushort4(os[0], os[1], os[2],  os[3]);
    sp[1] = make_ushort4(os[4], os[5], os[6],  os[7]);
    sp[2] = make_ushort4(os[8], os[9], os[10], os[11]);
}

// ---------- LayerNorm over H=768, wave per row ----------
__global__ __launch_bounds__(256) void ln_kernel(
    const float* __restrict__ Hbuf, const float* __restrict__ gamma,
    const float* __restrict__ beta, float* __restrict__ out)
{
    const int lane = threadIdx.x & 63;
    const int wave = threadIdx.x >> 6;
    const int r    = blockIdx.x * 4 + wave;
    const float* hr = Hbuf + (size_t)r * 768 + lane * 12;

    float v[12];
    {
        float4 a = *(const float4*)(hr);
        float4 b = *(const float4*)(hr + 4);
        float4 c = *(const float4*)(hr + 8);
        v[0]=a.x; v[1]=a.y; v[2]=a.z; v[3]=a.w;
        v[4]=b.x; v[5]=b.y; v[6]=b.z; v[7]=b.w;
        v[8]=c.x; v[9]=c.y; v[10]=c.z; v[11]=c.w;
    }
    float s = 0.f;
#pragma unroll
    for (int j = 0; j < 12; j++) s += v[j];
#pragma unroll
    for (int off = 32; off > 0; off >>= 1) s += __shfl_xor(s, off, 64);
    const float mu = s * (1.f / 768.f);
    float vs = 0.f;
#pragma unroll
    for (int j = 0; j < 12; j++) { float d = v[j] - mu; vs += d * d; }
#pragma unroll
    for (int off = 32; off > 0; off >>= 1) vs += __shfl_xor(vs, off, 64);
    const float rs = rsqrtf(vs * (1.f / 768.f) + 1e-12f);

    float o[12];
#pragma unroll
    for (int j = 0; j < 12; j++) {
        int h = lane * 12 + j;
        o[j] = (v[j] - mu) * rs * gamma[h] + beta[h];
    }
    float* orow = out + (size_t)r * 768 + lane * 12;
    *(float4*)(orow)     = make_float4(o[0], o[1], o[2],  o[3]);
    *(float4*)(orow + 4) = make_float4(o[4], o[5], o[6],  o[7]);
    *(float4*)(orow + 8) = make_float4(o[8], o[9], o[10], o[11]);
}

extern "C" void kernel_launch(void* const* d_in, const int* in_sizes, int n_in,
                              void* d_out, int out_size, void* d_ws, size_t ws_size,
                              hipStream_t stream)
{
    const float* x      = (const float*)d_in[0];
    const float* E      = (const float*)d_in[1];
    const int*   mask   = (const int*)d_in[2];
    const float* W1     = (const float*)d_in[3];
    const float* b1     = (const float*)d_in[4];
    const float* W2     = (const float*)d_in[5];
    const float* b2     = (const float*)d_in[6];
    const float* attn_W = (const float*)d_in[7];
    const float* gamma  = (const float*)d_in[8];
    const float* beta   = (const float*)d_in[9];
    float* out = (float*)d_out;

    const int BS = 8192, H = 768, M1 = 40960, KP = 256;

    char* p = (char*)d_ws;
    auto alloc = [&](size_t bytes) { char* q = p; p += (bytes + 255) & ~(size_t)255; return q; };
    __hip_bfloat16* xb    = (__hip_bfloat16*)alloc((size_t)BS * H * 2);    // 12.58 MB
    __hip_bfloat16* W2b   = (__hip_bfloat16*)alloc((size_t)H * H * 2);
    __hip_bfloat16* W2Tb  = (__hip_bfloat16*)alloc((size_t)H * H * 2);
    __hip_bfloat16* attnb = (__hip_bfloat16*)alloc((size_t)H * H * 2);
    __hip_bfloat16* Ctb   = (__hip_bfloat16*)alloc((size_t)H * H * 2);
    __hip_bfloat16* W1Tb  = (__hip_bfloat16*)alloc((size_t)H * KP * 2);
    __hip_bfloat16* Tb    = (__hip_bfloat16*)alloc((size_t)M1 * H * 2);    // 62.92 MB
    __hip_bfloat16* Eb    = (__hip_bfloat16*)alloc((size_t)M1 * KP * 2);   // 20.97 MB
    float* Hb = (float*)Tb;              // alias: Tb dead after attn
    __hip_bfloat16* Pb = Eb;             // alias: Eb dead after T-GEMM
    __hip_bfloat16* Sb = Pb;             // alias: same-wave read-then-write

    // 1) fat prep: transposes (768) + W2/attn cvt (144) + x cvt (768) + E pad (1280)
    prep_kernel<<<2960, 256, 0, stream>>>(x, xb, W2, W2b, attn_W, attnb,
                                          E, Eb, W1, W1Tb, W2Tb);

    // 2) Ct = W2 @ attn_W^T [36 blocks, first] + T = tanh(Eb@W1+b1) [1920 blocks]
    tct_kernel<<<1956, 256, 0, stream>>>(Eb, W1Tb, b1, Tb, W2b, attnb, Ctb);

    // 3) P = x @ Ct^T  (384 blocks, XCD-swizzled)
    mfma_gemm<false, false, false, true, 768, 768, 6><<<384, 256, 0, stream>>>(
        xb, Ctb, nullptr, nullptr, Pb);

    // 4) attention -> S
    attn_kernel<<<BS / 4, 256, 0, stream>>>(Tb, Pb, mask, Sb);

    // 5) H = x + S @ W2 + b2
    mfma_gemm<true, false, true, false, 768, 768, 6><<<384, 256, 0, stream>>>(
        Sb, W2Tb, b2, x, Hb);

    // 6) out = LN(H)*gamma + beta
    ln_kernel<<<BS / 4, 256, 0, stream>>>(Hb, gamma, beta, out);
}